// Round 3
// baseline (400.957 us; speedup 1.0000x reference)
//
#include <hip/hip_runtime.h>
#include <hip/hip_bf16.h>
#include <math.h>

typedef __bf16 bf16;
typedef __bf16 bf16x8 __attribute__((ext_vector_type(8)));
typedef float floatx4 __attribute__((ext_vector_type(4)));

#define GAS __attribute__((address_space(1)))
#define LAS __attribute__((address_space(3)))

static constexpr int B_ = 16, L_ = 4096, C_ = 512;
static constexpr int M_ = B_ * L_;   // 65536 rows (b,l)
static constexpr int K_ = 3 * C_;    // 1536

// ---- K1: fused prep. blocks [0,16384): cast x f32->bf16; [16384,19456): repack w_down.
__global__ void prep(const float* __restrict__ x, bf16* __restrict__ xb,
                     const float* __restrict__ wd, bf16* __restrict__ wr) {
    if (blockIdx.x < 16384) {
        const size_t i = ((size_t)blockIdx.x * 256 + threadIdx.x) * 8;
        floatx4 a = *(const floatx4*)(x + i);
        floatx4 b = *(const floatx4*)(x + i + 4);
        bf16x8 o;
#pragma unroll
        for (int j = 0; j < 4; ++j) { o[j] = (bf16)a[j]; o[4 + j] = (bf16)b[j]; }
        *(bf16x8*)(xb + i) = o;
    } else {
        int idx = (blockIdx.x - 16384) * 256 + threadIdx.x;   // 512*1536 total
        int o   = idx / K_;
        int rem = idx - o * K_;
        int kk  = rem >> 9;
        int i   = rem & 511;
        wr[idx] = (bf16)wd[o * K_ + i * 3 + kk];
    }
}

// ---- K2: dilated-conv-as-GEMM on the m201 8-phase template.
// 256x256 tile, BK=64, 8 waves (512 thr), per-wave C = 2x(64 rows) x 2x(32 cols),
// acc[2][4][2][2]=128 regs. Per K-tile: 4 phases, each
//   { ds_read new frag half | stage 1 future half-tile -> barrier -> lgkmcnt(0)
//     -> setprio(1) 16 MFMA setprio(0) -> barrier }.
// Stage schedule (prefetch distance 7 half-tiles, vmcnt(6) once per tile, never 0
// until tail): tile t ph0 stages (t+1).B.h0, ph1 (t+2).A.h0, ph2 (t+2).B.h1,
// ph3 (t+2).A.h1. Region safety: A.h0 last read ph0 < restage ph1; B.h1 last read
// ph1 < ph2; A.h1 last read ph2(+reuse ph3 in regs... read ph2 only) < ph3;
// B.h0 read ph0 (regs reused ph3), restaged next tile ph0 while other buffer active.
// Round-2 post-mortem: lockstep 2-phase schedule serializes LDS-read (~3000cyc) +
// MFMA (~2060cyc) + stage per K-tile (~6200cyc measured); 8-phase overlaps them.
__global__ __launch_bounds__(512, 2) void gemm_conv(
    const bf16* __restrict__ x, const bf16* __restrict__ wr,
    const float* __restrict__ bd, bf16* __restrict__ xp, float* __restrict__ sums)
{
    __shared__ bf16 As[2 * 256 * 64];   // 64 KB (2 K-tile buffers, 2 halves each)
    __shared__ bf16 Bs[2 * 256 * 64];   // 64 KB

    const int tid = threadIdx.x;        // 0..511
    // XCD swizzle: the 2 n-blocks of one m-tile land on the same XCD.
    const int u   = blockIdx.x;           // 0..511
    const int mb  = (u & 7) + 8 * (u >> 4);
    const int nb  = (u >> 3) & 1;
    const int m0  = mb * 256;
    const int n0  = nb * 256;

    const int wave = tid >> 6;            // 0..7
    const int lane = tid & 63;
    const int wm = wave & 1;              // 64-row subblock within each 128-half
    const int wn = wave >> 1;             // 32-col subblock within each 128-half
    const int tm = lane & 15;
    const int quad = lane >> 4;

    // acc[mh][mi][nh][ni]: output rows m0 + mh*128 + wm*64 + mi*16 + quad*4 + r,
    // cols n0 + nh*128 + wn*32 + ni*16 + tm
    floatx4 acc[2][4][2][2];
#pragma unroll
    for (int a = 0; a < 2; ++a)
#pragma unroll
        for (int b = 0; b < 4; ++b)
#pragma unroll
            for (int c = 0; c < 2; ++c)
#pragma unroll
                for (int d = 0; d < 2; ++d) acc[a][b][c][d] = floatx4{0.f, 0.f, 0.f, 0.f};

    // staging map: half-tile = 128 rows x 64 cols = 1024 chunks of 16B; 2 sweeps.
    // sweep j: qa = tid + 512j -> row qa>>3, landing chunk qa&7, source chunk XOR'd.
    const int r0  = tid >> 3;                       // 0..63  (sweep1 row = r0+64)
    const int c0s = (tid & 7) ^ (r0 & 7);           // same for sweep 1 (64 = 0 mod 8)

    auto stageA = [&](int t, int eta) {             // 2 global_load_lds
        if (t >= 24) return;
        const int kk = t >> 3, i0 = (t & 7) << 6;
        bf16* dst = As + (t & 1) * 16384 + eta * 8192 + tid * 8;
        int sr0 = m0 + eta * 128 + r0 + 2 * kk;      if (sr0 > M_ - 1) sr0 = M_ - 1;
        int sr1 = m0 + eta * 128 + r0 + 64 + 2 * kk; if (sr1 > M_ - 1) sr1 = M_ - 1;
        __builtin_amdgcn_global_load_lds((const GAS void*)(x + (size_t)sr0 * C_ + i0 + c0s * 8),
                                         (LAS void*)dst, 16, 0, 0);
        __builtin_amdgcn_global_load_lds((const GAS void*)(x + (size_t)sr1 * C_ + i0 + c0s * 8),
                                         (LAS void*)(dst + 4096), 16, 0, 0);
    };
    auto stageB = [&](int t, int eta) {             // 2 global_load_lds
        if (t >= 24) return;
        const int kk = t >> 3, i0 = (t & 7) << 6;
        bf16* dst = Bs + (t & 1) * 16384 + eta * 8192 + tid * 8;
        const bf16* s0 = wr + (size_t)(n0 + eta * 128 + r0) * K_ + kk * C_ + i0 + c0s * 8;
        __builtin_amdgcn_global_load_lds((const GAS void*)s0, (LAS void*)dst, 16, 0, 0);
        __builtin_amdgcn_global_load_lds((const GAS void*)(s0 + (size_t)64 * K_),
                                         (LAS void*)(dst + 4096), 16, 0, 0);
    };

    // read-side swizzled chunk offsets (elems), k-half 0/1; frag rows == tm mod 8
    const int xo0 = (quad ^ (tm & 7)) << 3;
    const int xo1 = ((4 + quad) ^ (tm & 7)) << 3;

    bf16x8 af[4][2];        // current A half: [mi][kh]
    bf16x8 bfr[2][2][2];    // both B halves kept live: [nh][ni][kh]

    // prologue: tile0 all 4 halves, then tile1's {A.h0, B.h1, A.h1} (B.h0 comes at
    // tile0 ph0). 14 loads; vmcnt(6) -> tile0's 8 landed.
    stageA(0, 0); stageB(0, 0); stageB(0, 1); stageA(0, 1);
    stageA(1, 0); stageB(1, 1); stageA(1, 1);
    asm volatile("s_waitcnt vmcnt(6)" ::: "memory");
    asm volatile("s_barrier" ::: "memory");

#pragma unroll 2
    for (int t = 0; t < 24; ++t) {
        const bf16* Ab = As + (t & 1) * 16384;
        const bf16* Bb = Bs + (t & 1) * 16384;

        // ---- phase 0: read af<-A.h0 (8), bfr[0]<-B.h0 (4); stage (t+1).B.h0; Q(0,0)
#pragma unroll
        for (int mi = 0; mi < 4; ++mi) {
            const bf16* p = Ab + (wm * 64 + mi * 16 + tm) * 64;
            af[mi][0] = *(const bf16x8*)(p + xo0);
            af[mi][1] = *(const bf16x8*)(p + xo1);
        }
#pragma unroll
        for (int ni = 0; ni < 2; ++ni) {
            const bf16* p = Bb + (wn * 32 + ni * 16 + tm) * 64;
            bfr[0][ni][0] = *(const bf16x8*)(p + xo0);
            bfr[0][ni][1] = *(const bf16x8*)(p + xo1);
        }
        stageB(t + 1, 0);
        asm volatile("s_waitcnt lgkmcnt(8)" ::: "memory");
        asm volatile("s_barrier" ::: "memory");
        asm volatile("s_waitcnt lgkmcnt(0)" ::: "memory");
        __builtin_amdgcn_s_setprio(1);
#pragma unroll
        for (int kh = 0; kh < 2; ++kh)
#pragma unroll
            for (int mi = 0; mi < 4; ++mi)
#pragma unroll
                for (int ni = 0; ni < 2; ++ni)
                    acc[0][mi][0][ni] = __builtin_amdgcn_mfma_f32_16x16x32_bf16(
                        af[mi][kh], bfr[0][ni][kh], acc[0][mi][0][ni], 0, 0, 0);
        __builtin_amdgcn_s_setprio(0);
        asm volatile("s_barrier" ::: "memory");

        // ---- phase 1: read bfr[1]<-B.h1 (4); stage (t+2).A.h0; Q(0,1)
#pragma unroll
        for (int ni = 0; ni < 2; ++ni) {
            const bf16* p = Bb + (128 + wn * 32 + ni * 16 + tm) * 64;
            bfr[1][ni][0] = *(const bf16x8*)(p + xo0);
            bfr[1][ni][1] = *(const bf16x8*)(p + xo1);
        }
        stageA(t + 2, 0);
        asm volatile("s_barrier" ::: "memory");
        asm volatile("s_waitcnt lgkmcnt(0)" ::: "memory");
        __builtin_amdgcn_s_setprio(1);
#pragma unroll
        for (int kh = 0; kh < 2; ++kh)
#pragma unroll
            for (int mi = 0; mi < 4; ++mi)
#pragma unroll
                for (int ni = 0; ni < 2; ++ni)
                    acc[0][mi][1][ni] = __builtin_amdgcn_mfma_f32_16x16x32_bf16(
                        af[mi][kh], bfr[1][ni][kh], acc[0][mi][1][ni], 0, 0, 0);
        __builtin_amdgcn_s_setprio(0);
        asm volatile("s_barrier" ::: "memory");

        // ---- phase 2: read af<-A.h1 (8); stage (t+2).B.h1; Q(1,1)
#pragma unroll
        for (int mi = 0; mi < 4; ++mi) {
            const bf16* p = Ab + (128 + wm * 64 + mi * 16 + tm) * 64;
            af[mi][0] = *(const bf16x8*)(p + xo0);
            af[mi][1] = *(const bf16x8*)(p + xo1);
        }
        stageB(t + 2, 1);
        asm volatile("s_barrier" ::: "memory");
        asm volatile("s_waitcnt lgkmcnt(0)" ::: "memory");
        __builtin_amdgcn_s_setprio(1);
#pragma unroll
        for (int kh = 0; kh < 2; ++kh)
#pragma unroll
            for (int mi = 0; mi < 4; ++mi)
#pragma unroll
                for (int ni = 0; ni < 2; ++ni)
                    acc[1][mi][1][ni] = __builtin_amdgcn_mfma_f32_16x16x32_bf16(
                        af[mi][kh], bfr[1][ni][kh], acc[1][mi][1][ni], 0, 0, 0);
        __builtin_amdgcn_s_setprio(0);
        asm volatile("s_barrier" ::: "memory");

        // ---- phase 3: no ds_read; stage (t+2).A.h1; counted vmcnt; Q(1,0)
        stageA(t + 2, 1);
        if (t < 22)       { asm volatile("s_waitcnt vmcnt(6)" ::: "memory"); }
        else if (t == 22) { asm volatile("s_waitcnt vmcnt(0)" ::: "memory"); }  // tail drain
        asm volatile("s_barrier" ::: "memory");
        __builtin_amdgcn_s_setprio(1);
#pragma unroll
        for (int kh = 0; kh < 2; ++kh)
#pragma unroll
            for (int mi = 0; mi < 4; ++mi)
#pragma unroll
                for (int ni = 0; ni < 2; ++ni)
                    acc[1][mi][0][ni] = __builtin_amdgcn_mfma_f32_16x16x32_bf16(
                        af[mi][kh], bfr[0][ni][kh], acc[1][mi][0][ni], 0, 0, 0);
        __builtin_amdgcn_s_setprio(0);
        asm volatile("s_barrier" ::: "memory");
    }

    // epilogue: + bias, store bf16, fused stats. C/D: col=lane&15, row=quad*4+reg.
    float bias[2][2], s[2][2], q[2][2];
#pragma unroll
    for (int nh = 0; nh < 2; ++nh)
#pragma unroll
        for (int ni = 0; ni < 2; ++ni) {
            bias[nh][ni] = bd[n0 + nh * 128 + wn * 32 + ni * 16 + tm];
            s[nh][ni] = 0.f; q[nh][ni] = 0.f;
        }

#pragma unroll
    for (int mh = 0; mh < 2; ++mh)
#pragma unroll
        for (int mi = 0; mi < 4; ++mi)
#pragma unroll
            for (int r = 0; r < 4; ++r) {
                const int m = m0 + mh * 128 + wm * 64 + mi * 16 + quad * 4 + r;
                const bool valid = (m & (L_ - 1)) < L_ - 4;   // exclude garbage boundary rows
                bf16* dst = xp + (size_t)m * C_ + n0 + wn * 32 + tm;
#pragma unroll
                for (int nh = 0; nh < 2; ++nh)
#pragma unroll
                    for (int ni = 0; ni < 2; ++ni) {
                        const float v = acc[mh][mi][nh][ni][r] + bias[nh][ni];
                        dst[nh * 128 + ni * 16] = (bf16)v;
                        if (valid) { s[nh][ni] += v; q[nh][ni] += v * v; }
                    }
            }
#pragma unroll
    for (int nh = 0; nh < 2; ++nh)
#pragma unroll
        for (int ni = 0; ni < 2; ++ni) {
            float sv = s[nh][ni], qv = q[nh][ni];
            sv += __shfl_xor(sv, 16); sv += __shfl_xor(sv, 32);
            qv += __shfl_xor(qv, 16); qv += __shfl_xor(qv, 32);
            if (quad == 0) {
                const int c = n0 + nh * 128 + wn * 32 + ni * 16 + tm;
                atomicAdd(&sums[c], sv);
                atomicAdd(&sums[C_ + c], qv);
            }
        }
}

// ---- K3: boundary rows l in [4092,4096): xp = w_pad . x + b_pad, plus their stats
__global__ void fixup(const float* __restrict__ x, const float* __restrict__ wp,
                      const float* __restrict__ bp, bf16* __restrict__ xp,
                      float* __restrict__ sums)
{
    const int b = blockIdx.x >> 2;
    const int j = blockIdx.x & 3;
    __shared__ float xrow[C_];
    for (int i = threadIdx.x; i < C_; i += 256)
        xrow[i] = x[(size_t)(b * L_ + j) * C_ + i];
    __syncthreads();
    for (int c = threadIdx.x; c < C_; c += 256) {
        const float* w = wp + (size_t)c * C_;
        float acc = 0.f;
#pragma unroll 4
        for (int i = 0; i < C_; i += 4) {
            floatx4 wv = *(const floatx4*)(w + i);
#pragma unroll
            for (int u = 0; u < 4; ++u) acc += wv[u] * xrow[i + u];
        }
        const float v = acc + bp[c];
        xp[(size_t)(b * L_ + 4092 + j) * C_ + c] = (bf16)v;
        atomicAdd(&sums[c], v);
        atomicAdd(&sums[C_ + c], v * v);
    }
}

// ---- K4: BN(from raw sums) -> ELU -> +residual(bf16) -> maxpool(3,2,pad1) -> [B,L/2,C] f32
__global__ void final_pool(const bf16* __restrict__ xp, const bf16* __restrict__ xb,
                           const float* __restrict__ sums, const float* __restrict__ gamma,
                           const float* __restrict__ beta, float* __restrict__ out)
{
    const int gid = blockIdx.x * 256 + threadIdx.x;  // B * 2048 * 64 groups of 8 ch
    const int cg = gid & 63;
    const int t  = (gid >> 6) & 2047;
    const int b  = gid >> 17;
    const int c0 = cg << 3;

    float sc[8], sh[8];
    const float invn = 1.0f / 65536.0f;
#pragma unroll
    for (int j = 0; j < 8; ++j) {
        const int c = c0 + j;
        float mean = sums[c] * invn;
        float var  = sums[C_ + c] * invn - mean * mean;
        float scale = gamma[c] * rsqrtf(var + 1e-5f);
        sc[j] = scale;
        sh[j] = beta[c] - mean * scale;
    }

    float best[8];
#pragma unroll
    for (int j = 0; j < 8; ++j) best[j] = -INFINITY;

#pragma unroll
    for (int dl = -1; dl <= 1; ++dl) {
        const int l = 2 * t + dl;
        if (l < 0) continue;                        // right edge never exceeds 4095
        const size_t off = (size_t)(b * L_ + l) * C_ + c0;
        bf16x8 xpv = *(const bf16x8*)(xp + off);
        bf16x8 xv  = *(const bf16x8*)(xb + off);
#pragma unroll
        for (int j = 0; j < 8; ++j) {
            float z = sc[j] * (float)xpv[j] + sh[j];
            float y = (z > 0.f) ? z : (__expf(z) - 1.f);
            y += (float)xv[j];
            best[j] = fmaxf(best[j], y);
        }
    }
    floatx4 o0, o1;
#pragma unroll
    for (int j = 0; j < 4; ++j) { o0[j] = best[j]; o1[j] = best[4 + j]; }
    *(floatx4*)(out + (size_t)gid * 8) = o0;
    *(floatx4*)(out + (size_t)gid * 8 + 4) = o1;
}

extern "C" void kernel_launch(void* const* d_in, const int* in_sizes, int n_in,
                              void* d_out, int out_size, void* d_ws, size_t ws_size,
                              hipStream_t stream)
{
    const float* x      = (const float*)d_in[0];
    const float* w_down = (const float*)d_in[1];
    const float* b_down = (const float*)d_in[2];
    const float* w_pad  = (const float*)d_in[3];
    const float* b_pad  = (const float*)d_in[4];
    const float* gamma  = (const float*)d_in[5];
    const float* beta   = (const float*)d_in[6];
    float* out = (float*)d_out;

    char* ws = (char*)d_ws;
    bf16*  xb   = (bf16*)ws;                                        // 64 MiB  [B*L][C] bf16 copy of x
    bf16*  xp   = (bf16*)(ws + (size_t)M_ * C_ * 2);                // 64 MiB  [B*L][C]
    bf16*  wr   = (bf16*)(ws + (size_t)M_ * C_ * 4);                // 1.5 MiB [O][K]
    float* sums = (float*)(ws + (size_t)M_ * C_ * 4 + (size_t)C_ * K_ * 2);  // 1024 f32

    hipMemsetAsync(sums, 0, 2 * C_ * sizeof(float), stream);
    prep<<<dim3(16384 + 3072), dim3(256), 0, stream>>>(x, xb, w_down, wr);
    gemm_conv<<<dim3(512), dim3(512), 0, stream>>>(xb, wr, b_down, xp, sums);
    fixup<<<dim3(64), dim3(256), 0, stream>>>(x, w_pad, b_pad, xp, sums);
    final_pool<<<dim3(8192), dim3(256), 0, stream>>>(xp, xb, sums, gamma, beta, out);
}